// Round 1
// baseline (618.560 us; speedup 1.0000x reference)
//
#include <hip/hip_runtime.h>

#define NB 256
#define DD 512
#define DKk 100
#define NT 7          // ceil(100/16) column tiles
#define CHUNK 16
#define SSTRIDE 224   // padded score-row stride (max N = 200)

typedef __attribute__((ext_vector_type(8))) short short8;
typedef __attribute__((ext_vector_type(4))) short short4v;
typedef __attribute__((ext_vector_type(4))) float f32x4;

struct AttendArgs {
  const float* feats[4];
  const float* wfeat[4];
  const float* wf[4];
  const float* bias[4];
  int   N[4];
  float coef[4];
};

// fp32 -> bf16 bits, round-to-nearest-even (normal values; inputs are N(0,1)-ish)
__device__ __forceinline__ short f2bf(float x) {
  unsigned u = __builtin_bit_cast(unsigned, x);
  unsigned r = (u + 0x7fffu + ((u >> 16) & 1u)) >> 16;
  return (short)r;
}

// ---------------------------------------------------------------------------
// Kernel A: scores[a][b][n] = bias[n] + sum_k wf[k] * tanh( feats[b,n,:] . w[:,k] )
// One block per (a,b). B (= w_feat) fragments preloaded to registers.
// A (= feats rows) staged fp32->bf16 in LDS, 16 rows per chunk.
// mfma_f32_16x16x32_bf16: A[m=lane&15][k=(lane>>4)*8+j], B[k][n=lane&15],
// D: col=lane&15, row=(lane>>4)*4+reg.
// ---------------------------------------------------------------------------
__global__ __launch_bounds__(256, 2)
void scores_kernel(AttendArgs args, float* __restrict__ scores_g) {
  const int a = blockIdx.x & 3;
  const int b = blockIdx.x >> 2;
  const int tid = threadIdx.x;
  const int lane = tid & 63;
  const int wave = tid >> 6;
  const int m = lane & 15;   // MFMA "n"-col lane (w column within tile) / A-row on load
  const int q = lane >> 4;   // quad
  const int N = args.N[a];
  const float* __restrict__ feats = args.feats[a] + (size_t)b * (size_t)N * DD;
  const float* __restrict__ wsrc = args.wfeat[a];
  const float* __restrict__ wfp  = args.wf[a];
  const float* __restrict__ bias = args.bias[a];
  float* __restrict__ rowbase = scores_g + (size_t)(a * NB + b) * SSTRIDE;

  __shared__ __align__(16) unsigned short f_lds[CHUNK][DD + 8]; // +8 pad: 2-way banks (free)
  __shared__ float score_red[CHUNK];

  // Preload w fragments for this wave's tiles {wave, wave+4} (tile 7 doesn't exist)
  short8 bfrag[2][16];
  float wfv[2];
  #pragma unroll
  for (int ti = 0; ti < 2; ++ti) {
    const int t = wave + 4 * ti;
    const int col = t * 16 + m;
    const bool ok = (t < NT) && (col < DKk);
    const int colc = ok ? col : 0;
    wfv[ti] = ok ? wfp[colc] : 0.f;
    #pragma unroll
    for (int ks = 0; ks < 16; ++ks) {
      short8 f;
      #pragma unroll
      for (int j = 0; j < 8; ++j) {
        const int d = ks * 32 + q * 8 + j;     // K index (0..511)
        const float v = wsrc[d * DKk + colc];  // w_feat[d][col], row-major (512,100)
        f[j] = ok ? f2bf(v) : (short)0;
      }
      bfrag[ti][ks] = f;
    }
  }

  const int nchunks = (N + CHUNK - 1) / CHUNK;
  for (int c = 0; c < nchunks; ++c) {
    const int n0 = c * CHUNK;
    __syncthreads();
    // Stage 16 rows x 512 cols (contiguous 32KB fp32) -> bf16 LDS; zero-pad tail rows
    #pragma unroll
    for (int it = 0; it < 8; ++it) {
      const int idx = tid + it * 256;   // 0..2047 float4 slots
      const int row = idx >> 7;
      const int c4 = idx & 127;
      float4 v = make_float4(0.f, 0.f, 0.f, 0.f);
      if (n0 + row < N)
        v = *reinterpret_cast<const float4*>(feats + (size_t)(n0 + row) * DD + (c4 << 2));
      short4v pk = { f2bf(v.x), f2bf(v.y), f2bf(v.z), f2bf(v.w) };
      *reinterpret_cast<short4v*>(&f_lds[row][c4 << 2]) = pk;
    }
    if (tid < CHUNK) score_red[tid] = 0.f;
    __syncthreads();

    f32x4 acc0 = {0.f, 0.f, 0.f, 0.f};
    f32x4 acc1 = {0.f, 0.f, 0.f, 0.f};
    #pragma unroll
    for (int ks = 0; ks < 16; ++ks) {
      const short8 af = *reinterpret_cast<const short8*>(&f_lds[m][ks * 32 + q * 8]);
      acc0 = __builtin_amdgcn_mfma_f32_16x16x32_bf16(af, bfrag[0][ks], acc0, 0, 0, 0);
      acc1 = __builtin_amdgcn_mfma_f32_16x16x32_bf16(af, bfrag[1][ks], acc1, 0, 0, 0);
    }

    // epilogue: per-lane tanh * wf, then reduce over the 16 col-lanes
    float part[4];
    #pragma unroll
    for (int r = 0; r < 4; ++r)
      part[r] = tanhf(acc0[r]) * wfv[0] + tanhf(acc1[r]) * wfv[1];
    #pragma unroll
    for (int mask = 1; mask <= 8; mask <<= 1) {
      #pragma unroll
      for (int r = 0; r < 4; ++r)
        part[r] += __shfl_xor(part[r], mask, 64);
    }
    if (m == 0) {
      #pragma unroll
      for (int r = 0; r < 4; ++r)
        atomicAdd(&score_red[q * 4 + r], part[r]);  // rows q*4+r, across 4 waves
    }
    __syncthreads();
    if (tid < CHUNK && (n0 + tid) < N)
      rowbase[n0 + tid] = score_red[tid] + bias[n0 + tid];
  }
}

// ---------------------------------------------------------------------------
// Kernel B: per (a,b): softmax over scores[0..N), then out[b,:] += coef/l * sum_n p_n * feats[b,n,:]
// 512 threads, thread owns one d. Coalesced fp32 feats reads.
// ---------------------------------------------------------------------------
__global__ __launch_bounds__(512, 2)
void softmax_wsum_kernel(AttendArgs args, const float* __restrict__ scores_g,
                         float* __restrict__ out) {
  const int a = blockIdx.x & 3;
  const int b = blockIdx.x >> 2;
  const int tid = threadIdx.x;
  const int N = args.N[a];
  const float* __restrict__ feats = args.feats[a] + (size_t)b * (size_t)N * DD;
  const float* __restrict__ srow = scores_g + (size_t)(a * NB + b) * SSTRIDE;

  __shared__ float p_lds[SSTRIDE];
  __shared__ float red[512];

  float pm = -1e30f;
  for (int n = tid; n < N; n += 512) {
    const float v = srow[n];
    p_lds[n] = v;
    pm = fmaxf(pm, v);
  }
  red[tid] = pm;
  __syncthreads();
  for (int s = 256; s > 0; s >>= 1) {
    if (tid < s) red[tid] = fmaxf(red[tid], red[tid + s]);
    __syncthreads();
  }
  const float mx = red[0];
  __syncthreads();
  float ps = 0.f;
  for (int n = tid; n < N; n += 512) {
    const float e = __expf(p_lds[n] - mx);
    p_lds[n] = e;
    ps += e;
  }
  red[tid] = ps;
  __syncthreads();
  for (int s = 256; s > 0; s >>= 1) {
    if (tid < s) red[tid] += red[tid + s];
    __syncthreads();
  }
  const float scale = args.coef[a] / red[0];

  float acc = 0.f;
  for (int n = 0; n < N; ++n)
    acc += p_lds[n] * feats[(size_t)n * DD + tid];
  atomicAdd(&out[(size_t)b * DD + tid], acc * scale);
}

extern "C" void kernel_launch(void* const* d_in, const int* in_sizes, int n_in,
                              void* d_out, int out_size, void* d_ws, size_t ws_size,
                              hipStream_t stream) {
  // d_in: 0 ifeature, 1 tfeature_h, 2 gfeature, 3 efeature,
  //       4+4i w_vi{i}, 5+4i w_vt{i}, 6+4i w_p{i}, 7+4i b{i}
  AttendArgs args;
  // attend0: feats=ifeature, w=w_vi0, wf=w_p0[:100] (vec_first=False), bias=b0, N=196
  args.feats[0] = (const float*)d_in[0];
  args.wfeat[0] = (const float*)d_in[4];
  args.wf[0]    = (const float*)d_in[6];
  args.bias[0]  = (const float*)d_in[7];
  args.N[0] = 196; args.coef[0] = 1.0f;
  // attend1: feats=tfeature_h, w=w_vt1, wf=w_p1[100:] (vec_first=True), bias=b1, N=200
  args.feats[1] = (const float*)d_in[1];
  args.wfeat[1] = (const float*)d_in[9];
  args.wf[1]    = (const float*)d_in[10] + 100;
  args.bias[1]  = (const float*)d_in[11];
  args.N[1] = 200; args.coef[1] = 1.0f;
  // attend2: feats=gfeature, w=w_vt2, wf=w_p2[100:], bias=b2, N=200
  args.feats[2] = (const float*)d_in[2];
  args.wfeat[2] = (const float*)d_in[13];
  args.wf[2]    = (const float*)d_in[14] + 100;
  args.bias[2]  = (const float*)d_in[15];
  args.N[2] = 200; args.coef[2] = 0.5f;
  // attend3: feats=efeature, w=w_vt3, wf=w_p3[100:], bias=b3, N=50
  args.feats[3] = (const float*)d_in[3];
  args.wfeat[3] = (const float*)d_in[17];
  args.wf[3]    = (const float*)d_in[18] + 100;
  args.bias[3]  = (const float*)d_in[19];
  args.N[3] = 50; args.coef[3] = 0.5f;

  float* scores = (float*)d_ws;  // 4*256*224 floats = 917504 B

  hipMemsetAsync(d_out, 0, (size_t)out_size * sizeof(float), stream);
  scores_kernel<<<dim3(4 * NB), dim3(256), 0, stream>>>(args, scores);
  softmax_wsum_kernel<<<dim3(4 * NB), dim3(512), 0, stream>>>(args, scores, (float*)d_out);
}

// Round 3
// 396.486 us; speedup vs baseline: 1.5601x; 1.5601x over previous
//
#include <hip/hip_runtime.h>

#define DD 512
#define DKk 100
#define NT 7          // ceil(100/16) column tiles
#define CHUNK 16
#define MAXN 208      // max padded N (200 -> 13 chunks * 16)
#define LDS_STRIDE 520  // shorts per staged row (+8 pad: 2-way banks, free)

typedef __attribute__((ext_vector_type(8))) short short8;
typedef __attribute__((ext_vector_type(4))) short short4v;
typedef __attribute__((ext_vector_type(4))) float f32x4;

struct AttendArgs {
  const float* feats[4];
  const float* wfeat[4];
  const float* wf[4];
  const float* bias[4];
  int   N[4];
  float coef[4];
};

// fp32 -> bf16 bits, round-to-nearest-even
__device__ __forceinline__ short f2bf(float x) {
  unsigned u = __builtin_bit_cast(unsigned, x);
  unsigned r = (u + 0x7fffu + ((u >> 16) & 1u)) >> 16;
  return (short)r;
}

__device__ __forceinline__ float fast_tanh(float x) {
  // tanh(x) = 1 - 2/(e^{2x}+1); exact at +-inf, ~1e-7 error, way under threshold
  const float e = __expf(2.0f * x);
  return 1.0f - 2.0f / (e + 1.0f);
}

// ---------------------------------------------------------------------------
// Setup: convert w_feat (512x100 fp32, row-major) into MFMA B-fragment-ordered
// bf16: wfrag[((a*7+t)*16+ks)*512 + lane*8 + j] = bf16(w[d][col]),
// d = ks*32 + (lane>>4)*8 + j, col = t*16 + (lane&15). Zero past col>=100.
// ---------------------------------------------------------------------------
__global__ void wprep_kernel(AttendArgs args, unsigned short* __restrict__ wfrag) {
  const int a = blockIdx.x / NT;
  const int t = blockIdx.x % NT;
  const int tid = threadIdx.x;
  const int lane = tid & 63;
  const int m = lane & 15;
  const int q = lane >> 4;
  const int kg = tid >> 6;      // 0..3
  const int col = t * 16 + m;
  const float* __restrict__ w = args.wfeat[a];
  unsigned short* __restrict__ dst = wfrag + (size_t)((a * NT + t) * 16) * 512;
  #pragma unroll
  for (int i = 0; i < 4; ++i) {
    const int ks = kg * 4 + i;
    short8 v;
    #pragma unroll
    for (int j = 0; j < 8; ++j) {
      const int d = ks * 32 + q * 8 + j;
      v[j] = (col < DKk) ? f2bf(w[d * DKk + col]) : (short)0;
    }
    *reinterpret_cast<short8*>(dst + (size_t)ks * 512 + lane * 8) = v;
  }
}

// ---------------------------------------------------------------------------
// Fused per-(a,b) kernel: scores (MFMA, software-pipelined staging) -> softmax
// -> weighted sum, all in one block. 512 threads = 8 waves; wave = col tile.
// mfma_f32_16x16x32_bf16: A[m=lane&15][k=(lane>>4)*8+j], B[k][n=lane&15],
// D: col=lane&15, row=(lane>>4)*4+reg  (verified in round 1).
// ---------------------------------------------------------------------------
__global__ __launch_bounds__(512, 2)
void fused_kernel(AttendArgs args, const unsigned short* __restrict__ wfrag,
                  float* __restrict__ out) {
  const int a = blockIdx.x & 3;        // interleave a for load balance (a=3 short)
  const int b = blockIdx.x >> 2;
  const int tid = threadIdx.x;
  const int lane = tid & 63;
  const int wave = tid >> 6;           // = col tile t (0..7; 7 is idle-compute)
  const int m = lane & 15;
  const int q = lane >> 4;
  const int N = args.N[a];
  const float* __restrict__ feats = args.feats[a] + (size_t)b * (size_t)N * DD;
  const float* __restrict__ wfp = args.wf[a];
  const float* __restrict__ bias = args.bias[a];

  __shared__ __align__(16) unsigned short f_lds[2][CHUNK][LDS_STRIDE];
  __shared__ float sc_part[8][MAXN];
  __shared__ float red[512];
  __shared__ float p_lds[MAXN];

  // --- B fragments for this wave's tile (coalesced, pre-formatted) ---
  short8 bfrag[16];
  float wfv = 0.f;
  if (wave < NT) {
    const int col = wave * 16 + m;
    wfv = (col < DKk) ? wfp[col] : 0.f;
    const unsigned short* src = wfrag + (size_t)((a * NT + wave) * 16) * 512 + lane * 8;
    #pragma unroll
    for (int ks = 0; ks < 16; ++ks)
      bfrag[ks] = *reinterpret_cast<const short8*>(src + (size_t)ks * 512);
  } else {
    #pragma unroll
    for (int ks = 0; ks < 16; ++ks) bfrag[ks] = short8(0);
  }

  const int nchunks = (N + CHUNK - 1) / CHUNK;

  // --- prefetch chunk 0 into registers (4 float4 / thread = 16 rows x 512) ---
  float4 pf[4];
  #pragma unroll
  for (int it = 0; it < 4; ++it) {
    const int idx = tid + it * 512;
    const int row = idx >> 7;
    const int c4 = idx & 127;
    pf[it] = (row < N)
      ? *reinterpret_cast<const float4*>(feats + (size_t)row * DD + (c4 << 2))
      : make_float4(0.f, 0.f, 0.f, 0.f);
  }

  for (int c = 0; c < nchunks; ++c) {
    const int bufc = c & 1;
    // stage regs (chunk c) -> bf16 LDS
    #pragma unroll
    for (int it = 0; it < 4; ++it) {
      const int idx = tid + it * 512;
      const int row = idx >> 7;
      const int c4 = idx & 127;
      short4v pk = { f2bf(pf[it].x), f2bf(pf[it].y), f2bf(pf[it].z), f2bf(pf[it].w) };
      *reinterpret_cast<short4v*>(&f_lds[bufc][row][c4 << 2]) = pk;
    }
    // issue prefetch of chunk c+1 (overlaps with MFMA below)
    if (c + 1 < nchunks) {
      const int n0n = (c + 1) * CHUNK;
      #pragma unroll
      for (int it = 0; it < 4; ++it) {
        const int idx = tid + it * 512;
        const int row = n0n + (idx >> 7);
        const int c4 = idx & 127;
        pf[it] = (row < N)
          ? *reinterpret_cast<const float4*>(feats + (size_t)row * DD + (c4 << 2))
          : make_float4(0.f, 0.f, 0.f, 0.f);
      }
    }
    __syncthreads();  // staging of c visible; buf[1-bufc] reads (iter c-1) done

    if (wave < NT) {
      f32x4 acc = {0.f, 0.f, 0.f, 0.f};
      #pragma unroll
      for (int ks = 0; ks < 16; ++ks) {
        const short8 af = *reinterpret_cast<const short8*>(&f_lds[bufc][m][ks * 32 + q * 8]);
        acc = __builtin_amdgcn_mfma_f32_16x16x32_bf16(af, bfrag[ks], acc, 0, 0, 0);
      }
      float part[4];
      #pragma unroll
      for (int r = 0; r < 4; ++r) part[r] = fast_tanh(acc[r]) * wfv;
      #pragma unroll
      for (int mask = 1; mask <= 8; mask <<= 1) {
        #pragma unroll
        for (int r = 0; r < 4; ++r) part[r] += __shfl_xor(part[r], mask, 64);
      }
      if (m == 0) {
        #pragma unroll
        for (int r = 0; r < 4; ++r) sc_part[wave][c * 16 + q * 4 + r] = part[r];
      }
    } else if (m == 0) {
      #pragma unroll
      for (int r = 0; r < 4; ++r) sc_part[7][c * 16 + q * 4 + r] = 0.f;
    }
    // no trailing barrier: next iter writes the other LDS buffer
  }
  __syncthreads();

  // --- reduce partials + bias, softmax over n (N <= 200 < 512: 1 val/thread) ---
  float sval = -1e30f;
  if (tid < N) {
    sval = sc_part[0][tid] + sc_part[1][tid] + sc_part[2][tid] + sc_part[3][tid]
         + sc_part[4][tid] + sc_part[5][tid] + sc_part[6][tid] + sc_part[7][tid]
         + bias[tid];
  }
  red[tid] = sval;
  __syncthreads();
  for (int s = 256; s > 0; s >>= 1) {
    if (tid < s) red[tid] = fmaxf(red[tid], red[tid + s]);
    __syncthreads();
  }
  const float mx = red[0];
  __syncthreads();
  const float e = (tid < N) ? __expf(sval - mx) : 0.f;
  // FIX (R2 bug): zero-fill p_lds[N..MAXN) — stale LDS from a previous block on
  // this CU was read by the unrolled phase-2 loop (a=3, N=50 -> p_lds[50..51]).
  if (tid < MAXN) p_lds[tid] = e;
  red[tid] = e;
  __syncthreads();
  for (int s = 256; s > 0; s >>= 1) {
    if (tid < s) red[tid] += red[tid + s];
    __syncthreads();
  }
  const float scale = args.coef[a] / red[0];

  // --- phase 2: out[b,:] += scale * sum_n p_n * feats[n,:]  (L2/L3-hot reread)
  // FIX (R2 bug): main loop over N&~3 + scalar tail — no OOB feats reads.
  float acc0 = 0.f, acc1 = 0.f;
  const float* __restrict__ fp = feats + tid;
  const int n4 = N & ~3;
  for (int n = 0; n < n4; n += 4) {
    acc0 += p_lds[n + 0] * fp[(size_t)(n + 0) * DD];
    acc1 += p_lds[n + 1] * fp[(size_t)(n + 1) * DD];
    acc0 += p_lds[n + 2] * fp[(size_t)(n + 2) * DD];
    acc1 += p_lds[n + 3] * fp[(size_t)(n + 3) * DD];
  }
  for (int n = n4; n < N; ++n)
    acc0 += p_lds[n] * fp[(size_t)n * DD];
  atomicAdd(&out[(size_t)b * DD + tid], (acc0 + acc1) * scale);
}

extern "C" void kernel_launch(void* const* d_in, const int* in_sizes, int n_in,
                              void* d_out, int out_size, void* d_ws, size_t ws_size,
                              hipStream_t stream) {
  AttendArgs args;
  args.feats[0] = (const float*)d_in[0];
  args.wfeat[0] = (const float*)d_in[4];
  args.wf[0]    = (const float*)d_in[6];          // vec_first=False: wf = w_p[:100]
  args.bias[0]  = (const float*)d_in[7];
  args.N[0] = 196; args.coef[0] = 1.0f;

  args.feats[1] = (const float*)d_in[1];
  args.wfeat[1] = (const float*)d_in[9];
  args.wf[1]    = (const float*)d_in[10] + 100;   // vec_first=True: wf = w_p[100:]
  args.bias[1]  = (const float*)d_in[11];
  args.N[1] = 200; args.coef[1] = 1.0f;

  args.feats[2] = (const float*)d_in[2];
  args.wfeat[2] = (const float*)d_in[13];
  args.wf[2]    = (const float*)d_in[14] + 100;
  args.bias[2]  = (const float*)d_in[15];
  args.N[2] = 200; args.coef[2] = 0.5f;

  args.feats[3] = (const float*)d_in[3];
  args.wfeat[3] = (const float*)d_in[17];
  args.wf[3]    = (const float*)d_in[18] + 100;
  args.bias[3]  = (const float*)d_in[19];
  args.N[3] = 50;  args.coef[3] = 0.5f;

  unsigned short* wfrag = (unsigned short*)d_ws;  // 4*7*16*512*2 = 458,752 B

  hipMemsetAsync(d_out, 0, (size_t)out_size * sizeof(float), stream);
  wprep_kernel<<<dim3(4 * NT), dim3(256), 0, stream>>>(args, wfrag);
  fused_kernel<<<dim3(4 * 256), dim3(512), 0, stream>>>(args, wfrag, (float*)d_out);
}